// Round 5
// baseline (257.225 us; speedup 1.0000x reference)
//
#include <hip/hip_runtime.h>
#include <hip/hip_bf16.h>

// WindowEmbedding forward: out[b,t, w*D+d] = (t-w>=0) ? in[b, t-w, d] : 0
// B=16, T=2048, D=256, W=7.
//
// Input-centric scatter, 4-way chunked for read MLP:
//  - each thread owns 4 input vec4s at stride TOTAL/4 (stride is a multiple
//    of 4*T rows, so t — and all boundary logic — is shared across chunks)
//  - 4 independent NT loads issue back-to-back, then up to 28 independent
//    NT stores: the store stream no longer drains between single-load stalls.
//  - input read exactly once (34 MB), output written exactly once (235 MB);
//    both non-temporal (no reuse on either side, keep L2 out of the way).
//  - rows t<6 also zero the never-written slots (w>t) of their own row.

typedef float vf4 __attribute__((ext_vector_type(4)));

constexpr int B  = 16;
constexpr int T  = 2048;
constexpr int D  = 256;
constexpr int W  = 7;
constexpr int D4 = D / 4;              // 64 vec4 per (b,t,w) segment = 1 wave
constexpr int ROW4 = W * D4;           // 448 vec4 per output row
constexpr int CHUNK = 4;
constexpr int TOTAL4 = B * T * D4;     // 2,097,152 input vec4s
constexpr int S = TOTAL4 / CHUNK;      // 524,288 vec4 chunk stride
constexpr int SROW = S / D4;           // 8,192 rows per chunk stride (mult of T)
constexpr int SOUT = SROW * ROW4;      // output vec4 offset per chunk

__global__ __launch_bounds__(256) void window_scatter4_kernel(
    const vf4* __restrict__ in, vf4* __restrict__ out) {
  int i0  = blockIdx.x * 256 + threadIdx.x;  // [0, S)
  int row = i0 >> 6;                         // b*T + t of chunk 0
  int dd  = i0 & 63;
  int t   = row & (T - 1);                   // identical for all 4 chunks

  vf4 v[CHUNK];
#pragma unroll
  for (int c = 0; c < CHUNK; ++c)
    v[c] = __builtin_nontemporal_load(&in[i0 + c * S]);

  int base = row * ROW4 + dd;

#pragma unroll
  for (int w = 0; w < W; ++w) {
    if (t + w < T) {                         // wave-uniform
#pragma unroll
      for (int c = 0; c < CHUNK; ++c)
        __builtin_nontemporal_store(v[c], &out[base + c * SOUT + w * (ROW4 + D4)]);
    }
  }

  // edge zeros: slots (t, w) with w > t are never produced by any scatter.
  if (t < W - 1) {
    vf4 z = {0.f, 0.f, 0.f, 0.f};
    for (int w = t + 1; w < W; ++w) {
#pragma unroll
      for (int c = 0; c < CHUNK; ++c)
        __builtin_nontemporal_store(z, &out[base + c * SOUT + w * D4]);
    }
  }
}

extern "C" void kernel_launch(void* const* d_in, const int* in_sizes, int n_in,
                              void* d_out, int out_size, void* d_ws, size_t ws_size,
                              hipStream_t stream) {
  const vf4* in = (const vf4*)d_in[0];
  vf4* out = (vf4*)d_out;
  window_scatter4_kernel<<<S / 256, 256, 0, stream>>>(in, out);
}

// Round 6
// 254.289 us; speedup vs baseline: 1.0115x; 1.0115x over previous
//
#include <hip/hip_runtime.h>
#include <hip/hip_bf16.h>

// WindowEmbedding forward: out[b,t, w*D+d] = (t-w>=0) ? in[b, t-w, d] : 0
// B=16, T=2048, D=256, W=7.
//
// Round 6: identical structure to round 5 (input-centric scatter, 4-way
// chunked), but PLAIN cached loads/stores instead of non-temporal — clean
// A/B on cache policy. Rationale: the 6.5 TB/s harness fill uses plain
// stores; the input is L2/L3-warm from the harness restore copy; NT was
// never isolated (round 2->4 conflated fusion with NT).

typedef float vf4 __attribute__((ext_vector_type(4)));

constexpr int B  = 16;
constexpr int T  = 2048;
constexpr int D  = 256;
constexpr int W  = 7;
constexpr int D4 = D / 4;              // 64 vec4 per (b,t,w) segment = 1 wave
constexpr int ROW4 = W * D4;           // 448 vec4 per output row
constexpr int CHUNK = 4;
constexpr int TOTAL4 = B * T * D4;     // 2,097,152 input vec4s
constexpr int S = TOTAL4 / CHUNK;      // 524,288 vec4 chunk stride
constexpr int SROW = S / D4;           // 8,192 rows per chunk stride (mult of T)
constexpr int SOUT = SROW * ROW4;      // output vec4 offset per chunk

__global__ __launch_bounds__(256) void window_scatter4_plain_kernel(
    const vf4* __restrict__ in, vf4* __restrict__ out) {
  int i0  = blockIdx.x * 256 + threadIdx.x;  // [0, S)
  int row = i0 >> 6;                         // b*T + t of chunk 0
  int dd  = i0 & 63;
  int t   = row & (T - 1);                   // identical for all 4 chunks

  vf4 v[CHUNK];
#pragma unroll
  for (int c = 0; c < CHUNK; ++c)
    v[c] = in[i0 + c * S];

  int base = row * ROW4 + dd;

#pragma unroll
  for (int w = 0; w < W; ++w) {
    if (t + w < T) {                         // wave-uniform
#pragma unroll
      for (int c = 0; c < CHUNK; ++c)
        out[base + c * SOUT + w * (ROW4 + D4)] = v[c];
    }
  }

  // edge zeros: slots (t, w) with w > t are never produced by any scatter.
  if (t < W - 1) {
    vf4 z = {0.f, 0.f, 0.f, 0.f};
    for (int w = t + 1; w < W; ++w) {
#pragma unroll
      for (int c = 0; c < CHUNK; ++c)
        out[base + c * SOUT + w * D4] = z;
    }
  }
}

extern "C" void kernel_launch(void* const* d_in, const int* in_sizes, int n_in,
                              void* d_out, int out_size, void* d_ws, size_t ws_size,
                              hipStream_t stream) {
  const vf4* in = (const vf4*)d_in[0];
  vf4* out = (vf4*)d_out;
  window_scatter4_plain_kernel<<<S / 256, 256, 0, stream>>>(in, out);
}